// Round 2
// baseline (361.937 us; speedup 1.0000x reference)
//
#include <hip/hip_runtime.h>
#include <stdint.h>

#define UNITS 64
#define UU 4096          // UNITS*UNITS
#define NG 50
#define NSLOT 51         // 50 gaussians + 1 bias slot
#define GAMMA_C 10.0f
#define STEP_C (30.0f / 49.0f)
#define NWIN 4           // gaussian window width (centers lo..lo+3)
#define NSL 5            // NWIN + bias slot

__device__ __forceinline__ float bf_lo(uint32_t u) { return __uint_as_float(u << 16); }
__device__ __forceinline__ float bf_hi(uint32_t u) { return __uint_as_float(u & 0xffff0000u); }

// A[g, i*64+j] = sum_k W1[g,k] * W2[k, i*64+j]   (g<50)
// A[50, ij]    = sum_k b1[k]  * W2[k, ij] + b2[ij]
__global__ void k_precompA(const float* __restrict__ W1, const float* __restrict__ b1,
                           const float* __restrict__ W2, const float* __restrict__ b2,
                           float* __restrict__ A) {
  int ij = blockIdx.x * 256 + threadIdx.x;   // 0..4095
  int g = blockIdx.y;                        // 0..50
  float acc = 0.f;
  if (g < NG) {
    const float* w1r = W1 + g * UNITS;
    #pragma unroll 8
    for (int k = 0; k < UNITS; ++k) acc = fmaf(w1r[k], W2[k * UU + ij], acc);
  } else {
    #pragma unroll 8
    for (int k = 0; k < UNITS; ++k) acc = fmaf(b1[k], W2[k * UU + ij], acc);
    acc += b2[ij];
  }
  A[g * UU + ij] = acc;
}

// T5[g, i, m] = sum_j A[g, i*64+j] * Wt[m, j]   -> stored bf16 (RNE)
__global__ void k_precompT5(const float* __restrict__ A, const float* __restrict__ Wt,
                            uint16_t* __restrict__ T5) {
  int idx = blockIdx.x * 256 + threadIdx.x;  // i*64 + m
  int g = blockIdx.y;
  int i = idx >> 6, m = idx & 63;
  const float* ar = A + g * UU + i * UNITS;
  const float* wr = Wt + m * UNITS;
  float acc = 0.f;
  #pragma unroll 8
  for (int j = 0; j < UNITS; ++j) acc = fmaf(ar[j], wr[j], acc);
  uint32_t u = __float_as_uint(acc);
  u += 0x7fffu + ((u >> 16) & 1u);           // round-to-nearest-even to bf16
  T5[g * UU + i * UNITS + m] = (uint16_t)(u >> 16);
}

#define ACC2(u, n0, n1) { a = fmaf(bf_lo(u), (n0), a); a = fmaf(bf_hi(u), (n1), a); }

// One wave per edge. Lane i computes filtered[e, i] and atomically scatters to msg[dst, i].
// mb-outer / slot-inner: 5 independent FMA chains, nf read from LDS broadcast (no reg array).
__global__ void __launch_bounds__(256, 6) k_edge(
    const float* __restrict__ nf, const int* __restrict__ ei,
    const float* __restrict__ dist, const uint16_t* __restrict__ T5,
    float* __restrict__ msg, int E) {
  __shared__ float nfs[4][UNITS];
  int w = threadIdx.x >> 6, lane = threadIdx.x & 63;
  int e = blockIdx.x * 4 + w;
  if (e >= E) return;                        // no block-wide barriers used: safe

  int src = ei[e];
  int dst = ei[E + e];
  float d = dist[e];

  nfs[w][lane] = nf[src * UNITS + lane];     // coalesced gather; same-wave RAW on LDS is ordered

  // gaussian window: centers lo..lo+3; nearest excluded center >= 2 steps away (df <= 3e-7)
  int lo = (int)floorf(d * (1.0f / STEP_C)) - 1;
  lo = min(max(lo, 0), NG - NWIN);
  float df[NSL];
  #pragma unroll
  for (int l = 0; l < NWIN; ++l) {
    float t = d - (float)(lo + l) * STEP_C;
    df[l] = __expf(-GAMMA_C * t * t);
  }
  df[NWIN] = 1.0f;                           // bias slot weight

  // per-slot byte offsets into T5 (row = (g*64+lane), 128 B per row)
  uint32_t off[NSL];
  #pragma unroll
  for (int l = 0; l < NSL; ++l) {
    int g = (l < NWIN) ? (lo + l) : NG;
    off[l] = (uint32_t)((g * UNITS + lane) << 7);
  }
  const char* base = (const char*)T5;

  float acc[NSL] = {0.f, 0.f, 0.f, 0.f, 0.f};
  #pragma unroll
  for (int mb = 0; mb < 8; ++mb) {
    float4 n0 = *reinterpret_cast<const float4*>(&nfs[w][mb * 8]);
    float4 n1 = *reinterpret_cast<const float4*>(&nfs[w][mb * 8 + 4]);
    #pragma unroll
    for (int l = 0; l < NSL; ++l) {
      uint4 u = *reinterpret_cast<const uint4*>(base + off[l] + (mb << 4));
      float a = acc[l];
      ACC2(u.x, n0.x, n0.y)
      ACC2(u.y, n0.z, n0.w)
      ACC2(u.z, n1.x, n1.y)
      ACC2(u.w, n1.z, n1.w)
      acc[l] = a;
    }
  }

  float tot = 0.f;
  #pragma unroll
  for (int l = 0; l < NSL; ++l) tot = fmaf(df[l], acc[l], tot);

  atomicAdd(&msg[dst * UNITS + lane], tot);
}

// out = softplus(msg) - ln(2), numerically stable
__global__ void k_final(const float* __restrict__ msg, float* __restrict__ out, int n) {
  int i = blockIdx.x * 256 + threadIdx.x;
  if (i >= n) return;
  float x = msg[i];
  float sp = (x > 0.f) ? (x + log1pf(__expf(-x))) : log1pf(__expf(x));
  out[i] = sp - 0.69314718056f;
}

extern "C" void kernel_launch(void* const* d_in, const int* in_sizes, int n_in,
                              void* d_out, int out_size, void* d_ws, size_t ws_size,
                              hipStream_t stream) {
  const float* nf   = (const float*)d_in[0];
  const int*   ei   = (const int*)d_in[1];
  const float* dist = (const float*)d_in[2];
  const float* W1   = (const float*)d_in[3];
  const float* b1   = (const float*)d_in[4];
  const float* W2   = (const float*)d_in[5];
  const float* b2   = (const float*)d_in[6];
  const float* Wt   = (const float*)d_in[7];
  float* out = (float*)d_out;

  int E = in_sizes[2];          // 50000
  int n_out = out_size;         // N_NODES * UNITS = 640000

  // workspace layout
  char* ws = (char*)d_ws;
  float*    A   = (float*)ws;                          // 51*4096*4  = 835584 B
  uint16_t* T5  = (uint16_t*)(ws + 835584);            // 51*4096*2  = 417792 B
  float*    msg = (float*)(ws + 835584 + 417792);      // 640000*4   = 2560000 B

  hipMemsetAsync(msg, 0, (size_t)n_out * sizeof(float), stream);

  k_precompA <<<dim3(16, NSLOT), 256, 0, stream>>>(W1, b1, W2, b2, A);
  k_precompT5<<<dim3(16, NSLOT), 256, 0, stream>>>(A, Wt, T5);
  k_edge     <<<(E + 3) / 4, 256, 0, stream>>>(nf, ei, dist, T5, msg, E);
  k_final    <<<(n_out + 255) / 256, 256, 0, stream>>>(msg, out, n_out);
}

// Round 3
// 95.380 us; speedup vs baseline: 3.7947x; 3.7947x over previous
//
#include <hip/hip_runtime.h>
#include <stdint.h>

#define UNITS 64
#define UU 4096          // UNITS*UNITS
#define NG 50
#define NSLOT 51         // 50 gaussians + 1 bias slot
#define GAMMA_C 10.0f
#define STEP_C (30.0f / 49.0f)
#define NWIN 4           // gaussian window width (centers lo..lo+3)
#define NSL 5            // NWIN + bias slot

__device__ __forceinline__ float bf_lo(uint32_t u) { return __uint_as_float(u << 16); }
__device__ __forceinline__ float bf_hi(uint32_t u) { return __uint_as_float(u & 0xffff0000u); }

// A[g, i*64+j] = sum_k W1[g,k] * W2[k, i*64+j]   (g<50)
// A[50, ij]    = sum_k b1[k]  * W2[k, ij] + b2[ij]
__global__ void k_precompA(const float* __restrict__ W1, const float* __restrict__ b1,
                           const float* __restrict__ W2, const float* __restrict__ b2,
                           float* __restrict__ A) {
  int ij = blockIdx.x * 256 + threadIdx.x;   // 0..4095
  int g = blockIdx.y;                        // 0..50
  float acc = 0.f;
  if (g < NG) {
    const float* w1r = W1 + g * UNITS;
    #pragma unroll 8
    for (int k = 0; k < UNITS; ++k) acc = fmaf(w1r[k], W2[k * UU + ij], acc);
  } else {
    #pragma unroll 8
    for (int k = 0; k < UNITS; ++k) acc = fmaf(b1[k], W2[k * UU + ij], acc);
    acc += b2[ij];
  }
  A[g * UU + ij] = acc;
}

// T5B[g][mb][i][m'] = sum_j A[g, i*64+j] * Wt[(mb*8+m'), j]   -> bf16 (RNE), blocked for
// coalesced edge-kernel loads: at fixed (g,mb), lane i reads 16B at offset
// g*8192 + mb*1024 + i*16 (64 lanes contiguous -> 1KB per instruction).
__global__ void k_precompT5(const float* __restrict__ A, const float* __restrict__ Wt,
                            uint16_t* __restrict__ T5B) {
  int idx = blockIdx.x * 256 + threadIdx.x;  // i*64 + m
  int g = blockIdx.y;
  int i = idx >> 6, m = idx & 63;
  const float* ar = A + g * UU + i * UNITS;
  const float* wr = Wt + m * UNITS;
  float acc = 0.f;
  #pragma unroll 8
  for (int j = 0; j < UNITS; ++j) acc = fmaf(ar[j], wr[j], acc);
  uint32_t u = __float_as_uint(acc);
  u += 0x7fffu + ((u >> 16) & 1u);           // round-to-nearest-even to bf16
  T5B[(((g << 3) + (m >> 3)) << 9) + (i << 3) + (m & 7)] = (uint16_t)(u >> 16);
}

#define ACC2(u, n0, n1) { a = fmaf(bf_lo(u), (n0), a); a = fmaf(bf_hi(u), (n1), a); }

// One wave per edge. Lane i computes filtered[e, i] and atomically scatters to msg[dst, i].
// mb-outer / slot-inner: 5 independent FMA chains; T5B loads fully coalesced.
__global__ void __launch_bounds__(256, 6) k_edge(
    const float* __restrict__ nf, const int* __restrict__ ei,
    const float* __restrict__ dist, const uint16_t* __restrict__ T5B,
    float* __restrict__ msg, int E) {
  __shared__ float nfs[4][UNITS];
  int w = threadIdx.x >> 6, lane = threadIdx.x & 63;
  int e = blockIdx.x * 4 + w;
  if (e >= E) return;                        // no block-wide barriers used: safe

  int src = ei[e];
  int dst = ei[E + e];
  float d = dist[e];

  nfs[w][lane] = nf[src * UNITS + lane];     // coalesced gather; same-wave RAW on LDS is ordered

  // gaussian window: centers lo..lo+3; nearest excluded center >= 2 steps away (df <= 3e-7)
  int lo = (int)floorf(d * (1.0f / STEP_C)) - 1;
  lo = min(max(lo, 0), NG - NWIN);
  float df[NSL];
  #pragma unroll
  for (int l = 0; l < NWIN; ++l) {
    float t = d - (float)(lo + l) * STEP_C;
    df[l] = __expf(-GAMMA_C * t * t);
  }
  df[NWIN] = 1.0f;                           // bias slot weight

  // per-slot byte offsets into blocked T5: g*8192 + lane*16 (+ mb*1024 in loop)
  uint32_t off[NSL];
  #pragma unroll
  for (int l = 0; l < NSL; ++l) {
    int g = (l < NWIN) ? (lo + l) : NG;
    off[l] = (uint32_t)((g << 13) + (lane << 4));
  }
  const char* base = (const char*)T5B;

  float acc[NSL] = {0.f, 0.f, 0.f, 0.f, 0.f};
  #pragma unroll
  for (int mb = 0; mb < 8; ++mb) {
    float4 n0 = *reinterpret_cast<const float4*>(&nfs[w][mb * 8]);
    float4 n1 = *reinterpret_cast<const float4*>(&nfs[w][mb * 8 + 4]);
    #pragma unroll
    for (int l = 0; l < NSL; ++l) {
      uint4 u = *reinterpret_cast<const uint4*>(base + off[l] + (mb << 10));
      float a = acc[l];
      ACC2(u.x, n0.x, n0.y)
      ACC2(u.y, n0.z, n0.w)
      ACC2(u.z, n1.x, n1.y)
      ACC2(u.w, n1.z, n1.w)
      acc[l] = a;
    }
  }

  float tot = 0.f;
  #pragma unroll
  for (int l = 0; l < NSL; ++l) tot = fmaf(df[l], acc[l], tot);

  atomicAdd(&msg[dst * UNITS + lane], tot);
}

// out = softplus(msg) - ln(2), numerically stable
__global__ void k_final(const float* __restrict__ msg, float* __restrict__ out, int n) {
  int i = blockIdx.x * 256 + threadIdx.x;
  if (i >= n) return;
  float x = msg[i];
  float sp = (x > 0.f) ? (x + log1pf(__expf(-x))) : log1pf(__expf(x));
  out[i] = sp - 0.69314718056f;
}

extern "C" void kernel_launch(void* const* d_in, const int* in_sizes, int n_in,
                              void* d_out, int out_size, void* d_ws, size_t ws_size,
                              hipStream_t stream) {
  const float* nf   = (const float*)d_in[0];
  const int*   ei   = (const int*)d_in[1];
  const float* dist = (const float*)d_in[2];
  const float* W1   = (const float*)d_in[3];
  const float* b1   = (const float*)d_in[4];
  const float* W2   = (const float*)d_in[5];
  const float* b2   = (const float*)d_in[6];
  const float* Wt   = (const float*)d_in[7];
  float* out = (float*)d_out;

  int E = in_sizes[2];          // 50000
  int n_out = out_size;         // N_NODES * UNITS = 640000

  // workspace layout
  char* ws = (char*)d_ws;
  float*    A   = (float*)ws;                          // 51*4096*4  = 835584 B
  uint16_t* T5B = (uint16_t*)(ws + 835584);            // 51*4096*2  = 417792 B (blocked)
  float*    msg = (float*)(ws + 835584 + 417792);      // 640000*4   = 2560000 B

  hipMemsetAsync(msg, 0, (size_t)n_out * sizeof(float), stream);

  k_precompA <<<dim3(16, NSLOT), 256, 0, stream>>>(W1, b1, W2, b2, A);
  k_precompT5<<<dim3(16, NSLOT), 256, 0, stream>>>(A, Wt, T5B);
  k_edge     <<<(E + 3) / 4, 256, 0, stream>>>(nf, ei, dist, T5B, msg, E);
  k_final    <<<(n_out + 255) / 256, 256, 0, stream>>>(msg, out, n_out);
}

// Round 5
// 68.569 us; speedup vs baseline: 5.2784x; 1.3910x over previous
//
#include <hip/hip_runtime.h>
#include <stdint.h>

#define UNITS 64
#define UU 4096          // UNITS*UNITS
#define NG 50
#define NSLOT 51         // 50 gaussians + 1 bias slot
#define GAMMA_C 10.0f
#define STEP_C (30.0f / 49.0f)
#define NWIN 4           // gaussian window width (centers lo..lo+3)
#define NSL 5            // NWIN + bias slot

typedef __attribute__((ext_vector_type(8))) short bf16x8;
typedef __attribute__((ext_vector_type(4))) float f32x4;

__device__ __forceinline__ float bf_lo(uint32_t u) { return __uint_as_float(u << 16); }
__device__ __forceinline__ float bf_hi(uint32_t u) { return __uint_as_float(u & 0xffff0000u); }
__device__ __forceinline__ float bfu(uint16_t v) { return __uint_as_float(((uint32_t)v) << 16); }
__device__ __forceinline__ uint16_t f2bf(float x) {
  uint32_t u = __float_as_uint(x);
  u += 0x7fffu + ((u >> 16) & 1u);           // RNE to bf16
  return (uint16_t)(u >> 16);
}

// A[g, i*64+j] = sum_k W1[g,k] * W2[k, i*64+j]   (g<50)
// A[50, ij]    = sum_k b1[k]  * W2[k, ij] + b2[ij]
__global__ void k_precompA(const float* __restrict__ W1, const float* __restrict__ b1,
                           const float* __restrict__ W2, const float* __restrict__ b2,
                           float* __restrict__ A) {
  int ij = blockIdx.x * 256 + threadIdx.x;   // 0..4095
  int g = blockIdx.y;                        // 0..50
  float acc = 0.f;
  if (g < NG) {
    const float* w1r = W1 + g * UNITS;
    #pragma unroll 8
    for (int k = 0; k < UNITS; ++k) acc = fmaf(w1r[k], W2[k * UU + ij], acc);
  } else {
    #pragma unroll 8
    for (int k = 0; k < UNITS; ++k) acc = fmaf(b1[k], W2[k * UU + ij], acc);
    acc += b2[ij];
  }
  A[g * UU + ij] = acc;
}

// T5B[g][mb][i][m'] = sum_j A[g, i*64+j] * Wt[(mb*8+m'), j]  -> bf16, blocked:
// byte addr = g*8192 + mb*1024 + i*16 + m'*2
__global__ void k_precompT5(const float* __restrict__ A, const float* __restrict__ Wt,
                            uint16_t* __restrict__ T5B) {
  int idx = blockIdx.x * 256 + threadIdx.x;  // i*64 + m
  int g = blockIdx.y;
  int i = idx >> 6, m = idx & 63;
  const float* ar = A + g * UU + i * UNITS;
  const float* wr = Wt + m * UNITS;
  float acc = 0.f;
  #pragma unroll 8
  for (int j = 0; j < UNITS; ++j) acc = fmaf(ar[j], wr[j], acc);
  T5B[(((g << 3) + (m >> 3)) << 9) + (i << 3) + (m & 7)] = f2bf(acc);
}

// nf f32 -> bf16
__global__ void k_nf2bf(const float* __restrict__ nf, uint16_t* __restrict__ nfb, int n) {
  int i = blockIdx.x * 256 + threadIdx.x;
  if (i < n) nfb[i] = f2bf(nf[i]);
}

// Y[g][n][i] = sum_m T5[g][i][m] * nf[n][m]  == nf @ B, B[k=m][n=i] = T5B[g][k>>3][i][k&7]
// Dense bf16 MFMA GEMM. Block: 256 thr = 4 waves; wave w owns 32 node-rows (2 MFMA strips).
__global__ void __launch_bounds__(256) k_ygemm(const uint16_t* __restrict__ nfb,
                                               const uint16_t* __restrict__ T5B,
                                               uint16_t* __restrict__ Ybf, int NN) {
  int w = threadIdx.x >> 6, l = threadIdx.x & 63;
  int g = blockIdx.y;
  int base = blockIdx.x * 128 + w * 32;
  int lr = l & 15, lg = l >> 4;

  // B fragments: lane l, k = kk*32 + lg*8 + j, col = nt*16 + lr
  // byte = g*8192 + (kk*4+lg)*1024 + (nt*16+lr)*16  -> 16B contiguous per lane
  bf16x8 bfr[2][4];
  const char* bb = (const char*)T5B + (g << 13) + (lg << 10) + (lr << 4);
  #pragma unroll
  for (int kk = 0; kk < 2; ++kk)
    #pragma unroll
    for (int nt = 0; nt < 4; ++nt)
      bfr[kk][nt] = *reinterpret_cast<const bf16x8*>(bb + (kk << 12) + (nt << 8));

  // A fragments: lane l, row = l&15 (node), k = kk*32 + lg*8 + j
  bf16x8 afr[2][2];
  #pragma unroll
  for (int ms = 0; ms < 2; ++ms) {
    int node = base + ms * 16 + lr;
    if (node >= NN) node = NN - 1;             // clamp: garbage rows never stored
    const char* ab = (const char*)nfb + node * 128 + (lg << 4);
    afr[ms][0] = *reinterpret_cast<const bf16x8*>(ab);
    afr[ms][1] = *reinterpret_cast<const bf16x8*>(ab + 64);
  }

  f32x4 acc[2][4] = {};
  #pragma unroll
  for (int ms = 0; ms < 2; ++ms)
    #pragma unroll
    for (int kk = 0; kk < 2; ++kk)
      #pragma unroll
      for (int nt = 0; nt < 4; ++nt)
        acc[ms][nt] = __builtin_amdgcn_mfma_f32_16x16x32_bf16(afr[ms][kk], bfr[kk][nt],
                                                              acc[ms][nt], 0, 0, 0);

  // C/D (m89-verified): col = l&15, row = (l>>4)*4 + q
  #pragma unroll
  for (int ms = 0; ms < 2; ++ms) {
    #pragma unroll
    for (int q = 0; q < 4; ++q) {
      int node = base + ms * 16 + lg * 4 + q;
      if (node < NN) {
        uint16_t* yrow = Ybf + (((size_t)g * NN + node) << 6);
        #pragma unroll
        for (int nt = 0; nt < 4; ++nt)
          yrow[nt * 16 + lr] = f2bf(acc[ms][nt][q]);
      }
    }
  }
}

// One wave per edge: 5 coalesced 128B row-gathers from Y + 4 FMAs, scatter to msg.
__global__ void __launch_bounds__(256) k_edge2(const int* __restrict__ ei,
                                               const float* __restrict__ dist,
                                               const uint16_t* __restrict__ Ybf,
                                               float* __restrict__ msg, int E, int NN) {
  int w = threadIdx.x >> 6, lane = threadIdx.x & 63;
  int e = blockIdx.x * 4 + w;
  if (e >= E) return;
  int src = ei[e], dst = ei[E + e];
  float d = dist[e];

  int lo = (int)floorf(d * (1.0f / STEP_C)) - 1;
  lo = min(max(lo, 0), NG - NWIN);

  const uint16_t* yb = Ybf + ((size_t)src << 6) + lane;   // + g*NN*64 per slot
  size_t gstride = (size_t)NN << 6;
  float tot = bfu(yb[(size_t)NG * gstride]);              // bias slot, weight 1
  #pragma unroll
  for (int l = 0; l < NWIN; ++l) {
    float t = d - (float)(lo + l) * STEP_C;
    float dfv = __expf(-GAMMA_C * t * t);
    tot = fmaf(dfv, bfu(yb[(size_t)(lo + l) * gstride]), tot);
  }
  atomicAdd(&msg[dst * UNITS + lane], tot);
}

#define ACC2(u, n0, n1) { a = fmaf(bf_lo(u), (n0), a); a = fmaf(bf_hi(u), (n1), a); }

// FALLBACK (round-3 path) if ws_size can't hold Y.
__global__ void __launch_bounds__(256, 6) k_edge(
    const float* __restrict__ nf, const int* __restrict__ ei,
    const float* __restrict__ dist, const uint16_t* __restrict__ T5B,
    float* __restrict__ msg, int E) {
  __shared__ float nfs[4][UNITS];
  int w = threadIdx.x >> 6, lane = threadIdx.x & 63;
  int e = blockIdx.x * 4 + w;
  if (e >= E) return;
  int src = ei[e];
  int dst = ei[E + e];
  float d = dist[e];
  nfs[w][lane] = nf[src * UNITS + lane];
  int lo = (int)floorf(d * (1.0f / STEP_C)) - 1;
  lo = min(max(lo, 0), NG - NWIN);
  float df[NSL];
  #pragma unroll
  for (int l = 0; l < NWIN; ++l) {
    float t = d - (float)(lo + l) * STEP_C;
    df[l] = __expf(-GAMMA_C * t * t);
  }
  df[NWIN] = 1.0f;
  uint32_t off[NSL];
  #pragma unroll
  for (int l = 0; l < NSL; ++l) {
    int g = (l < NWIN) ? (lo + l) : NG;
    off[l] = (uint32_t)((g << 13) + (lane << 4));
  }
  const char* base = (const char*)T5B;
  float acc[NSL] = {0.f, 0.f, 0.f, 0.f, 0.f};
  #pragma unroll
  for (int mb = 0; mb < 8; ++mb) {
    float4 n0 = *reinterpret_cast<const float4*>(&nfs[w][mb * 8]);
    float4 n1 = *reinterpret_cast<const float4*>(&nfs[w][mb * 8 + 4]);
    #pragma unroll
    for (int l = 0; l < NSL; ++l) {
      uint4 u = *reinterpret_cast<const uint4*>(base + off[l] + (mb << 10));
      float a = acc[l];
      ACC2(u.x, n0.x, n0.y)
      ACC2(u.y, n0.z, n0.w)
      ACC2(u.z, n1.x, n1.y)
      ACC2(u.w, n1.z, n1.w)
      acc[l] = a;
    }
  }
  float tot = 0.f;
  #pragma unroll
  for (int l = 0; l < NSL; ++l) tot = fmaf(df[l], acc[l], tot);
  atomicAdd(&msg[dst * UNITS + lane], tot);
}

// out = softplus(msg) - ln(2), numerically stable
__global__ void k_final(const float* __restrict__ msg, float* __restrict__ out, int n) {
  int i = blockIdx.x * 256 + threadIdx.x;
  if (i >= n) return;
  float x = msg[i];
  float sp = (x > 0.f) ? (x + log1pf(__expf(-x))) : log1pf(__expf(x));
  out[i] = sp - 0.69314718056f;
}

extern "C" void kernel_launch(void* const* d_in, const int* in_sizes, int n_in,
                              void* d_out, int out_size, void* d_ws, size_t ws_size,
                              hipStream_t stream) {
  const float* nf   = (const float*)d_in[0];
  const int*   ei   = (const int*)d_in[1];
  const float* dist = (const float*)d_in[2];
  const float* W1   = (const float*)d_in[3];
  const float* b1   = (const float*)d_in[4];
  const float* W2   = (const float*)d_in[5];
  const float* b2   = (const float*)d_in[6];
  const float* Wt   = (const float*)d_in[7];
  float* out = (float*)d_out;

  int E = in_sizes[2];               // 50000
  int NN = in_sizes[0] / UNITS;      // 10000
  int n_out = out_size;              // NN * UNITS

  // workspace layout
  char* ws = (char*)d_ws;
  size_t off_T5  = 835584;                                  // A: 51*4096*4
  size_t off_msg = off_T5 + 417792;                         // T5B: 51*4096*2
  size_t off_nfb = off_msg + (size_t)n_out * 4;             // msg
  size_t off_Y   = off_nfb + (size_t)n_out * 2;             // nfb
  size_t need    = off_Y + (size_t)NSLOT * NN * UNITS * 2;  // Ybf: ~65.3 MB

  float*    A   = (float*)ws;
  uint16_t* T5B = (uint16_t*)(ws + off_T5);
  float*    msg = (float*)(ws + off_msg);

  hipMemsetAsync(msg, 0, (size_t)n_out * sizeof(float), stream);
  k_precompA <<<dim3(16, NSLOT), 256, 0, stream>>>(W1, b1, W2, b2, A);
  k_precompT5<<<dim3(16, NSLOT), 256, 0, stream>>>(A, Wt, T5B);

  if (ws_size >= need) {
    uint16_t* nfb = (uint16_t*)(ws + off_nfb);
    uint16_t* Ybf = (uint16_t*)(ws + off_Y);
    k_nf2bf <<<(n_out + 255) / 256, 256, 0, stream>>>(nf, nfb, n_out);
    k_ygemm <<<dim3((NN + 127) / 128, NSLOT), 256, 0, stream>>>(nfb, T5B, Ybf, NN);
    k_edge2 <<<(E + 3) / 4, 256, 0, stream>>>(ei, dist, Ybf, msg, E, NN);
  } else {
    k_edge  <<<(E + 3) / 4, 256, 0, stream>>>(nf, ei, dist, T5B, msg, E);
  }
  k_final <<<(n_out + 255) / 256, 256, 0, stream>>>(msg, out, n_out);
}